// Round 11
// baseline (236.491 us; speedup 1.0000x reference)
//
#include <hip/hip_runtime.h>
#include <cfloat>
#include <cmath>

// Problem: VectorQuantizer. inputs [16,8,512,64] fp32 (N=65536 rows, D=64),
// weight [512,64] fp32 (K=512). Outputs concat fp32:
//   [0] loss | [1..4194304] quantized_st | [4194305] perplexity | [4194306..] encodings (N*K)
//
// Lessons encoded:
//  - 1024-thr blocks pinned at 64 VGPR; 512-thr + launch_bounds unlocks 128+ (r10).
//  - encodings stores per-instruction DENSE (contiguous 512B) else L2 partial-line
//    RMW costs +60MB fetch AND write (r8 vs r10: FETCH 77->10MB).
//  - W chunk-major float4 [16][512], k^(c&7) swizzle: <=2-way LDS conflicts (r6).
//  - LDS pipe is the limiter at 8 rows/tile (W reads 1024 b128/wave); 16 rows/tile
//    halves W reads. s[16][8] needs ~190 VGPR -> launch_bounds(512,1).

#define OFF_LOSS  0
#define OFF_QUANT 1
#define OFF_PERP  4194305
#define OFF_ENC   4194306
#define VQ_EPS  1.1920929e-7f

// ws layout (u32): [0] sse(float) | [16..527] counts | [544..1055] wn (float)
#define WS_CNT 16
#define WS_WN  544

__global__ void vq_init(const float* __restrict__ w, unsigned* __restrict__ ws) {
    int t = threadIdx.x;  // 1024
    if (t < 544) ws[t] = 0u;
    if (t < 512) {
        const float4* wr = (const float4*)(w + (t << 6));
        float n = 0.f;
#pragma unroll
        for (int c = 0; c < 16; ++c) {
            float4 v = wr[c];
            n = fmaf(v.x, v.x, n);
            n = fmaf(v.y, v.y, n);
            n = fmaf(v.z, v.z, n);
            n = fmaf(v.w, v.w, n);
        }
        ((float*)ws)[WS_WN + t] = n;
    }
}

__global__ void __launch_bounds__(512, 1)
vq_main(const float* __restrict__ x, const float* __restrict__ w,
        float* __restrict__ out, float* __restrict__ ws)
{
    extern __shared__ float smem[];
    float* wt   = smem;            // chunk-major W, float4 view [16][512], code k at k^(c&7); 128 KB
    float* xlds = smem + 64 * 512; // [8 waves][16 rows][64], 32 KB

    const int t    = threadIdx.x;
    const int lane = t & 63;
    const int wid  = t >> 6;
    const float* wsf = (const float*)ws;

    // ---- stage W: coalesced global float4 reads; swizzled LDS writes
    {
        float4* wf4w = (float4*)wt;
        const float4* w4 = (const float4*)w;
#pragma unroll
        for (int i = 0; i < 16; ++i) {
            int e = t + (i << 9);            // float4 index into w [512][16]
            int k = e >> 4;
            int c = e & 15;
            wf4w[(c << 9) + (k ^ (c & 7))] = w4[e];
        }
    }

    // ---- per-lane ||w_k||^2 for codes k=j*64+lane (precomputed by vq_init)
    float wn[8];
#pragma unroll
    for (int j = 0; j < 8; ++j) wn[j] = wsf[WS_WN + (j << 6) + lane];

    __syncthreads();

    float sse = 0.f;
    const int waveRow0 = (blockIdx.x << 8) + (wid << 5);  // 256 rows/block, 32/wave
    float* myx = xlds + (wid << 10);                      // [16][64]
    const float4* wf4 = (const float4*)wt;
    const float4* xf4 = (const float4*)myx;

    for (int iter = 0; iter < 2; ++iter) {
        const int row0 = waveRow0 + (iter << 4);   // 16 rows per tile

        // ---- stage 16 rows of x (wave-private; DS in-order within wave);
        //      lane holds floats [16q,16q+16) of row lane>>2 -> octets 2q,2q+1
        float xn_bc;
        {
            const float* src = x + ((size_t)row0 << 6) + (lane << 4);
            float4 p0 = *(const float4*)src;
            float4 p1 = *(const float4*)(src + 4);
            float4 p2 = *(const float4*)(src + 8);
            float4 p3 = *(const float4*)(src + 12);
            int r  = lane >> 2;
            int d0 = (lane & 3) << 4;
            *(float4*)(myx + (r << 6) + d0)      = p0;
            *(float4*)(myx + (r << 6) + d0 + 4)  = p1;
            *(float4*)(myx + (r << 6) + d0 + 8)  = p2;
            *(float4*)(myx + (r << 6) + d0 + 12) = p3;
            // octet sums (sequential 8) then tree — identical order to the
            // validated ((s0+s1)+(s2+s3))+((s4+s5)+(s6+s7)) reduction
            float soA = p0.x*p0.x + p0.y*p0.y + p0.z*p0.z + p0.w*p0.w
                      + p1.x*p1.x + p1.y*p1.y + p1.z*p1.z + p1.w*p1.w;
            float soB = p2.x*p2.x + p2.y*p2.y + p2.z*p2.z + p2.w*p2.w
                      + p3.x*p3.x + p3.y*p3.y + p3.z*p3.z + p3.w*p3.w;
            float a = soA + soB;               // so[2q] + so[2q+1]
            a += __shfl_xor(a, 1);
            a += __shfl_xor(a, 2);
            xn_bc = a;  // lanes 4r..4r+3 hold ||x_row(r)||^2 (lane 4r = canonical)
        }

        // ---- s[r][j] = x_row(row0+r) . w_code(j*64+lane); W read once per
        //      (c,j) amortized over 16 rows; strict d-ascending fma (bit-exact)
        float s[16][8];
#pragma unroll
        for (int r = 0; r < 16; ++r)
#pragma unroll
            for (int j = 0; j < 8; ++j) s[r][j] = 0.f;

#pragma unroll 1
        for (int c = 0; c < 16; ++c) {
            const int lbase = (c << 9) + (lane ^ (c & 7));
            float4 wq4[8];
#pragma unroll
            for (int j = 0; j < 8; ++j) wq4[j] = wf4[lbase + (j << 6)];
#pragma unroll
            for (int r = 0; r < 16; ++r) {
                float4 xq = xf4[(r << 4) + c];   // LDS broadcast read
#pragma unroll
                for (int j = 0; j < 8; ++j) {
                    float acc = s[r][j];
                    acc = fmaf(xq.x, wq4[j].x, acc);
                    acc = fmaf(xq.y, wq4[j].y, acc);
                    acc = fmaf(xq.z, wq4[j].z, acc);
                    acc = fmaf(xq.w, wq4[j].w, acc);
                    s[r][j] = acc;
                }
            }
        }

        // ---- argmin per row (identical formula + tie-break, validated r4-r10)
        int bk_arr[16];
#pragma unroll
        for (int r = 0; r < 16; ++r) {
            float xn = __shfl(xn_bc, r << 2);
            float bv = FLT_MAX;
            int   bk = 0;
#pragma unroll
            for (int j = 0; j < 8; ++j) {
                float dv = (xn + wn[j]) - 2.0f * s[r][j];
                if (dv < bv) { bv = dv; bk = (j << 6) + lane; }
            }
#pragma unroll
            for (int off = 1; off < 64; off <<= 1) {
                float ov = __shfl_xor(bv, off);
                int   ok = __shfl_xor(bk, off);
                if (ov < bv || (ov == bv && ok < bk)) { bv = ov; bk = ok; }
            }
            bk_arr[r] = bk;
        }

        // ---- gather codebook rows (L2-resident)
        float wq[16];
#pragma unroll
        for (int r = 0; r < 16; ++r) wq[r] = w[((size_t)bk_arr[r] << 6) + lane];

        // ---- outputs: quantized_st, sse, one-hot (dense contiguous float2
        //      stores), histogram
#pragma unroll
        for (int r = 0; r < 16; ++r) {
            const int row = row0 + r;
            float xval = myx[(r << 6) + lane];
            float q    = wq[r];
            out[OFF_QUANT + ((size_t)row << 6) + lane] = xval + (q - xval);
            float df = q - xval;
            sse = fmaf(df, df, sse);

            int kk = bk_arr[r];
            float2* ebase = (float2*)(out + OFF_ENC + ((size_t)row << 9));
#pragma unroll
            for (int m = 0; m < 4; ++m) {
                int b = (m << 7) + (lane << 1);
                float2 f;
                f.x = (kk == b)     ? 1.f : 0.f;
                f.y = (kk == b + 1) ? 1.f : 0.f;
                ebase[(m << 6) + lane] = f;   // contiguous 512B per instruction
            }
            if (lane == r) atomicAdd(((unsigned*)ws) + WS_CNT + kk, 1u);
        }
    }

    // ---- loss partial
#pragma unroll
    for (int off = 1; off < 64; off <<= 1) sse += __shfl_xor(sse, off);
    if (lane == 0) atomicAdd((float*)ws, sse);
}

__global__ void vq_fin(const unsigned* __restrict__ ws, float* __restrict__ out)
{
    __shared__ float red[8];
    int t = threadIdx.x;   // 512 threads
    unsigned c = ws[WS_CNT + t];
    float p = (float)c * (1.0f / 65536.0f);
    float v = p * logf(p + VQ_EPS);
#pragma unroll
    for (int off = 1; off < 64; off <<= 1) v += __shfl_xor(v, off);
    if ((t & 63) == 0) red[t >> 6] = v;
    __syncthreads();
    if (t == 0) {
        float s2 = 0.f;
#pragma unroll
        for (int i = 0; i < 8; ++i) s2 += red[i];
        out[OFF_PERP] = expf(-s2);
        float sse = ((const float*)ws)[0];
        float m = sse * (1.0f / 4194304.0f);
        out[OFF_LOSS] = m + 0.25f * m;
    }
}

extern "C" void kernel_launch(void* const* d_in, const int* in_sizes, int n_in,
                              void* d_out, int out_size, void* d_ws, size_t ws_size,
                              hipStream_t stream) {
    const float* x = (const float*)d_in[0];
    const float* w = (const float*)d_in[1];
    float* out = (float*)d_out;
    unsigned* ws = (unsigned*)d_ws;

    const size_t smem = (size_t)(64 * 512 + 8 * 16 * 64) * 4;  // 160 KiB exactly
    (void)hipFuncSetAttribute((const void*)vq_main,
                              hipFuncAttributeMaxDynamicSharedMemorySize, (int)smem);

    hipLaunchKernelGGL(vq_init, dim3(1), dim3(1024), 0, stream, w, ws);
    hipLaunchKernelGGL(vq_main, dim3(256), dim3(512), smem, stream, x, w, out, (float*)ws);
    hipLaunchKernelGGL(vq_fin,  dim3(1), dim3(512), 0, stream, ws, out);
}